// Round 1
// baseline (321.195 us; speedup 1.0000x reference)
//
#include <hip/hip_runtime.h>

// Sparse 3D conv (Cin=1, Cout=16) as a weighted scatter-add:
//   out[out_idx[m], c] += feats[in_idx[m]] * weight[k_idx[m], c]
// One thread per (m, c) pair; 16 consecutive lanes handle one rulebook
// entry's 16 output channels (64 contiguous bytes of atomics).

__global__ void sparse_conv_scatter(const float* __restrict__ feats,
                                    const float* __restrict__ weight,
                                    const int* __restrict__ in_idx,
                                    const int* __restrict__ out_idx,
                                    const int* __restrict__ k_idx,
                                    float* __restrict__ out,
                                    int M) {
    long long t = (long long)blockIdx.x * blockDim.x + threadIdx.x;
    int m = (int)(t >> 4);
    int c = (int)(t & 15);
    if (m >= M) return;
    int i = in_idx[m];
    int o = out_idx[m];
    int k = k_idx[m];
    float f = feats[i];
    float w = weight[k * 16 + c];
    atomicAdd(out + (long long)o * 16 + c, f * w);
}

extern "C" void kernel_launch(void* const* d_in, const int* in_sizes, int n_in,
                              void* d_out, int out_size, void* d_ws, size_t ws_size,
                              hipStream_t stream) {
    const float* feats  = (const float*)d_in[0];
    const float* weight = (const float*)d_in[1];
    const int*   in_idx = (const int*)d_in[2];
    const int*   out_idx= (const int*)d_in[3];
    const int*   k_idx  = (const int*)d_in[4];
    float*       out    = (float*)d_out;

    const int M = in_sizes[2];  // rulebook length

    // d_out is poisoned to 0xAA before every timed launch — zero it.
    hipMemsetAsync(d_out, 0, (size_t)out_size * sizeof(float), stream);

    const long long total = (long long)M * 16;
    const int block = 256;
    const long long grid = (total + block - 1) / block;
    sparse_conv_scatter<<<(int)grid, block, 0, stream>>>(
        feats, weight, in_idx, out_idx, k_idx, out, M);
}